// Round 13
// baseline (48.218 us; speedup 1.0000x reference)
//
#include <hip/hip_runtime.h>

// NoiseLearnModule: out = x + where(0<=bin<16, eps * sigmoid(params[f,bin]) * 0.1, 0)
// bin = searchsorted(bins[f], x, side='right') - 1
// x,eps [65536,256] f32; bins [256,17] f32; params [256*16] f32.
//
// R13 = R9 (zero-LDS, 1 feature/thread, fused cndmask scan+select, U=4) + :
//  1. NON-TEMPORAL stores: out is streaming write-once data; nt bypasses
//     cache allocation -> no read-for-ownership traffic on the write path.
//  2. Validity folded into the chain endpoints: start s=(e[0]<=x)?sg[0]:0,
//     end s=(x<e[16])?s:0 — two cndmasks instead of cmp+cmp+and+cndmask.
// Loads stay cached (x/eps are L3-resident on timed replays).

#define NFEAT 256
#define NBINS 16
#define NEDGE 17
#define NOISE_SCALE 0.1f

__global__ __launch_bounds__(256, 4) void noise_learn_kernel(
    const float* __restrict__ x,
    const float* __restrict__ bins,
    const float* __restrict__ eps,
    const float* __restrict__ params,
    float* __restrict__ out,
    int total)
{
    const int t = threadIdx.x;               // == feature id

    // Prologue: tables (compiler will do what it does; R9 showed this shape
    // still runs at the floor despite VGPR=32 remat).
    float ed[NEDGE];
    #pragma unroll
    for (int i = 0; i < NEDGE; ++i)
        ed[i] = bins[t * NEDGE + i];

    float sg[NBINS];                         // pre-scaled: 0.1 * sigmoid(p)
    #pragma unroll
    for (int k = 0; k < NBINS; ++k)
        sg[k] = NOISE_SCALE / (1.0f + __expf(-params[t * NBINS + k]));

    const int n = gridDim.x * 256;           // multiple of 256 -> feature invariant
    const int gid = blockIdx.x * 256 + t;

// Fused scan+select with validity folded into the endpoints.
#define PROC(xv, ev, res) do {                                           \
        float s_ = (ed[0] <= (xv)) ? sg[0] : 0.0f;                       \
        s_ = (ed[1]  <= (xv)) ? sg[1]  : s_;                             \
        s_ = (ed[2]  <= (xv)) ? sg[2]  : s_;                             \
        s_ = (ed[3]  <= (xv)) ? sg[3]  : s_;                             \
        s_ = (ed[4]  <= (xv)) ? sg[4]  : s_;                             \
        s_ = (ed[5]  <= (xv)) ? sg[5]  : s_;                             \
        s_ = (ed[6]  <= (xv)) ? sg[6]  : s_;                             \
        s_ = (ed[7]  <= (xv)) ? sg[7]  : s_;                             \
        s_ = (ed[8]  <= (xv)) ? sg[8]  : s_;                             \
        s_ = (ed[9]  <= (xv)) ? sg[9]  : s_;                             \
        s_ = (ed[10] <= (xv)) ? sg[10] : s_;                             \
        s_ = (ed[11] <= (xv)) ? sg[11] : s_;                             \
        s_ = (ed[12] <= (xv)) ? sg[12] : s_;                             \
        s_ = (ed[13] <= (xv)) ? sg[13] : s_;                             \
        s_ = (ed[14] <= (xv)) ? sg[14] : s_;                             \
        s_ = (ed[15] <= (xv)) ? sg[15] : s_;                             \
        s_ = ((xv) < ed[16]) ? s_ : 0.0f;                                \
        (res) = fmaf((ev), s_, (xv));                                    \
    } while (0)

    // total = 16,777,216 = 2048*256*4*8 -> exactly 8 guard-free iterations.
    for (int base = gid; base + 3 * n < total; base += 4 * n) {
        const int gA = base, gB = base + n, gC = base + 2 * n, gD = base + 3 * n;

        const float xA = x[gA], xB = x[gB], xC = x[gC], xD = x[gD];
        const float pA = eps[gA], pB = eps[gB], pC = eps[gC], pD = eps[gD];

        float rA, rB, rC, rD;
        PROC(xA, pA, rA);
        PROC(xB, pB, rB);
        PROC(xC, pC, rC);
        PROC(xD, pD, rD);

        // Non-temporal streaming stores: no cache allocation, no RFO.
        __builtin_nontemporal_store(rA, &out[gA]);
        __builtin_nontemporal_store(rB, &out[gB]);
        __builtin_nontemporal_store(rC, &out[gC]);
        __builtin_nontemporal_store(rD, &out[gD]);
    }
#undef PROC
}

extern "C" void kernel_launch(void* const* d_in, const int* in_sizes, int n_in,
                              void* d_out, int out_size, void* d_ws, size_t ws_size,
                              hipStream_t stream) {
    const float* x      = (const float*)d_in[0];
    const float* bins   = (const float*)d_in[1];
    const float* eps    = (const float*)d_in[2];
    const float* params = (const float*)d_in[3];
    float* out = (float*)d_out;

    dim3 block(256);
    dim3 grid(2048);   // zero LDS; 8 iterations of U=4 per thread, no tail
    noise_learn_kernel<<<grid, block, 0, stream>>>(x, bins, eps, params, out, out_size);
}

// Round 14
// 38.168 us; speedup vs baseline: 1.2633x; 1.2633x over previous
//
#include <hip/hip_runtime.h>

// NoiseLearnModule: out = x + where(0<=bin<16, eps * sigmoid(params[f,bin]) * 0.1, 0)
// bin = searchsorted(bins[f], x, side='right') - 1
// x,eps [65536,256] f32; bins [256,17] f32; params [256*16] f32.
//
// R14 = R9 (zero-LDS, 1 feature/thread, fused cndmask scan+select, U=4,
// plain cached stores — R13 proved nt stores cost +9.5 µs) with ONE change:
// the prologue's 33 scattered scalar loads become 9 vector loads.
//   bins row (68 B stride, 4 B aligned):  4x dwordx4 via aligned(4) vector + 1 scalar
//   params row (64 B aligned):            4x float4
// Cuts the kernel-start TA/L1 address-pipe storm ~3.7x.

typedef float f4u __attribute__((ext_vector_type(4), aligned(4)));  // 4B-aligned float4

#define NFEAT 256
#define NBINS 16
#define NEDGE 17
#define NOISE_SCALE 0.1f

__global__ __launch_bounds__(256, 4) void noise_learn_kernel(
    const float* __restrict__ x,
    const float* __restrict__ bins,
    const float* __restrict__ eps,
    const float* __restrict__ params,
    float* __restrict__ out,
    int total)
{
    const int t = threadIdx.x;               // == feature id

    // Vectorized prologue: 5 loads for bins, 4 for params.
    float ed[NEDGE];
    {
        const f4u* br = reinterpret_cast<const f4u*>(bins + t * NEDGE);
        const f4u b0 = br[0], b1 = br[1], b2 = br[2], b3 = br[3];
        ed[0] = b0[0]; ed[1] = b0[1]; ed[2]  = b0[2];  ed[3]  = b0[3];
        ed[4] = b1[0]; ed[5] = b1[1]; ed[6]  = b1[2];  ed[7]  = b1[3];
        ed[8] = b2[0]; ed[9] = b2[1]; ed[10] = b2[2];  ed[11] = b2[3];
        ed[12] = b3[0]; ed[13] = b3[1]; ed[14] = b3[2]; ed[15] = b3[3];
        ed[16] = bins[t * NEDGE + 16];
    }

    float sg[NBINS];                         // pre-scaled: 0.1 * sigmoid(p)
    {
        const float4* pr = reinterpret_cast<const float4*>(params + t * NBINS); // 64B-aligned
        const float4 p0 = pr[0], p1 = pr[1], p2 = pr[2], p3 = pr[3];
        const float pp[NBINS] = { p0.x, p0.y, p0.z, p0.w,  p1.x, p1.y, p1.z, p1.w,
                                  p2.x, p2.y, p2.z, p2.w,  p3.x, p3.y, p3.z, p3.w };
        #pragma unroll
        for (int k = 0; k < NBINS; ++k)
            sg[k] = NOISE_SCALE / (1.0f + __expf(-pp[k]));
    }

    const int n = gridDim.x * 256;           // multiple of 256 -> feature invariant
    const int gid = blockIdx.x * 256 + t;

// Fused scan+select with validity folded into the endpoints.
#define PROC(xv, ev, res) do {                                           \
        float s_ = (ed[0] <= (xv)) ? sg[0] : 0.0f;                       \
        s_ = (ed[1]  <= (xv)) ? sg[1]  : s_;                             \
        s_ = (ed[2]  <= (xv)) ? sg[2]  : s_;                             \
        s_ = (ed[3]  <= (xv)) ? sg[3]  : s_;                             \
        s_ = (ed[4]  <= (xv)) ? sg[4]  : s_;                             \
        s_ = (ed[5]  <= (xv)) ? sg[5]  : s_;                             \
        s_ = (ed[6]  <= (xv)) ? sg[6]  : s_;                             \
        s_ = (ed[7]  <= (xv)) ? sg[7]  : s_;                             \
        s_ = (ed[8]  <= (xv)) ? sg[8]  : s_;                             \
        s_ = (ed[9]  <= (xv)) ? sg[9]  : s_;                             \
        s_ = (ed[10] <= (xv)) ? sg[10] : s_;                             \
        s_ = (ed[11] <= (xv)) ? sg[11] : s_;                             \
        s_ = (ed[12] <= (xv)) ? sg[12] : s_;                             \
        s_ = (ed[13] <= (xv)) ? sg[13] : s_;                             \
        s_ = (ed[14] <= (xv)) ? sg[14] : s_;                             \
        s_ = (ed[15] <= (xv)) ? sg[15] : s_;                             \
        s_ = ((xv) < ed[16]) ? s_ : 0.0f;                                \
        (res) = fmaf((ev), s_, (xv));                                    \
    } while (0)

    // total = 16,777,216 = 2048*256*4*8 -> exactly 8 guard-free iterations.
    for (int base = gid; base + 3 * n < total; base += 4 * n) {
        const int gA = base, gB = base + n, gC = base + 2 * n, gD = base + 3 * n;

        const float xA = x[gA], xB = x[gB], xC = x[gC], xD = x[gD];
        const float pA = eps[gA], pB = eps[gB], pC = eps[gC], pD = eps[gD];

        float rA, rB, rC, rD;
        PROC(xA, pA, rA);
        PROC(xB, pB, rB);
        PROC(xC, pC, rC);
        PROC(xD, pD, rD);

        out[gA] = rA;
        out[gB] = rB;
        out[gC] = rC;
        out[gD] = rD;
    }
#undef PROC
}

extern "C" void kernel_launch(void* const* d_in, const int* in_sizes, int n_in,
                              void* d_out, int out_size, void* d_ws, size_t ws_size,
                              hipStream_t stream) {
    const float* x      = (const float*)d_in[0];
    const float* bins   = (const float*)d_in[1];
    const float* eps    = (const float*)d_in[2];
    const float* params = (const float*)d_in[3];
    float* out = (float*)d_out;

    dim3 block(256);
    dim3 grid(2048);   // zero LDS; 8 iterations of U=4 per thread, no tail
    noise_learn_kernel<<<grid, block, 0, stream>>>(x, bins, eps, params, out, out_size);
}

// Round 15
// 37.124 us; speedup vs baseline: 1.2988x; 1.0281x over previous
//
#include <hip/hip_runtime.h>

// NoiseLearnModule: out = x + where(0<=bin<16, eps * sigmoid(params[f,bin]) * 0.1, 0)
// bin = searchsorted(bins[f], x, side='right') - 1
// x,eps [65536,256] f32; bins [256,17] f32; params [256*16] f32.
//
// R15 = R14 (zero-LDS, 1 feature/thread, fused cndmask scan+select, U=4,
// vectorized prologue, cached stores) with ONE change: SLAB BLOCKING.
// Block b owns rows [32b, 32b+32) — a contiguous 32 KB window. The U=4
// accesses are 4 CONSECUTIVE rows (1 KB apart, not 2 MB apart); each block's
// read/write streams are contiguous slabs -> DRAM page & L2 sector locality
// for the 64 MB HBM write drain. Everything else identical to R14.

typedef float f4u __attribute__((ext_vector_type(4), aligned(4)));  // 4B-aligned float4

#define NFEAT 256
#define NBINS 16
#define NEDGE 17
#define ROWS_PER_BLOCK 32
#define NOISE_SCALE 0.1f

__global__ __launch_bounds__(256, 4) void noise_learn_kernel(
    const float* __restrict__ x,
    const float* __restrict__ bins,
    const float* __restrict__ eps,
    const float* __restrict__ params,
    float* __restrict__ out,
    int total)
{
    const int t = threadIdx.x;               // == feature id

    // Vectorized prologue (R14): 5 loads for bins, 4 for params.
    float ed[NEDGE];
    {
        const f4u* br = reinterpret_cast<const f4u*>(bins + t * NEDGE);
        const f4u b0 = br[0], b1 = br[1], b2 = br[2], b3 = br[3];
        ed[0] = b0[0]; ed[1] = b0[1]; ed[2]  = b0[2];  ed[3]  = b0[3];
        ed[4] = b1[0]; ed[5] = b1[1]; ed[6]  = b1[2];  ed[7]  = b1[3];
        ed[8] = b2[0]; ed[9] = b2[1]; ed[10] = b2[2];  ed[11] = b2[3];
        ed[12] = b3[0]; ed[13] = b3[1]; ed[14] = b3[2]; ed[15] = b3[3];
        ed[16] = bins[t * NEDGE + 16];
    }

    float sg[NBINS];                         // pre-scaled: 0.1 * sigmoid(p)
    {
        const float4* pr = reinterpret_cast<const float4*>(params + t * NBINS); // 64B-aligned
        const float4 p0 = pr[0], p1 = pr[1], p2 = pr[2], p3 = pr[3];
        const float pp[NBINS] = { p0.x, p0.y, p0.z, p0.w,  p1.x, p1.y, p1.z, p1.w,
                                  p2.x, p2.y, p2.z, p2.w,  p3.x, p3.y, p3.z, p3.w };
        #pragma unroll
        for (int k = 0; k < NBINS; ++k)
            sg[k] = NOISE_SCALE / (1.0f + __expf(-pp[k]));
    }

// Fused scan+select with validity folded into the endpoints.
#define PROC(xv, ev, res) do {                                           \
        float s_ = (ed[0] <= (xv)) ? sg[0] : 0.0f;                       \
        s_ = (ed[1]  <= (xv)) ? sg[1]  : s_;                             \
        s_ = (ed[2]  <= (xv)) ? sg[2]  : s_;                             \
        s_ = (ed[3]  <= (xv)) ? sg[3]  : s_;                             \
        s_ = (ed[4]  <= (xv)) ? sg[4]  : s_;                             \
        s_ = (ed[5]  <= (xv)) ? sg[5]  : s_;                             \
        s_ = (ed[6]  <= (xv)) ? sg[6]  : s_;                             \
        s_ = (ed[7]  <= (xv)) ? sg[7]  : s_;                             \
        s_ = (ed[8]  <= (xv)) ? sg[8]  : s_;                             \
        s_ = (ed[9]  <= (xv)) ? sg[9]  : s_;                             \
        s_ = (ed[10] <= (xv)) ? sg[10] : s_;                             \
        s_ = (ed[11] <= (xv)) ? sg[11] : s_;                             \
        s_ = (ed[12] <= (xv)) ? sg[12] : s_;                             \
        s_ = (ed[13] <= (xv)) ? sg[13] : s_;                             \
        s_ = (ed[14] <= (xv)) ? sg[14] : s_;                             \
        s_ = (ed[15] <= (xv)) ? sg[15] : s_;                             \
        s_ = ((xv) < ed[16]) ? s_ : 0.0f;                                \
        (res) = fmaf((ev), s_, (xv));                                    \
    } while (0)

    // Slab: block b covers element range [b*32*256, (b+1)*32*256).
    // 8 iterations x 4 consecutive rows, all guard-free (65536 = 2048*32).
    const int base0 = blockIdx.x * (ROWS_PER_BLOCK * NFEAT) + t;

    for (int j = 0; j < ROWS_PER_BLOCK / 4; ++j) {
        const int g = base0 + j * (4 * NFEAT);
        const int gA = g, gB = g + NFEAT, gC = g + 2 * NFEAT, gD = g + 3 * NFEAT;

        const float xA = x[gA], xB = x[gB], xC = x[gC], xD = x[gD];
        const float pA = eps[gA], pB = eps[gB], pC = eps[gC], pD = eps[gD];

        float rA, rB, rC, rD;
        PROC(xA, pA, rA);
        PROC(xB, pB, rB);
        PROC(xC, pC, rC);
        PROC(xD, pD, rD);

        out[gA] = rA;
        out[gB] = rB;
        out[gC] = rC;
        out[gD] = rD;
    }
#undef PROC
}

extern "C" void kernel_launch(void* const* d_in, const int* in_sizes, int n_in,
                              void* d_out, int out_size, void* d_ws, size_t ws_size,
                              hipStream_t stream) {
    const float* x      = (const float*)d_in[0];
    const float* bins   = (const float*)d_in[1];
    const float* eps    = (const float*)d_in[2];
    const float* params = (const float*)d_in[3];
    float* out = (float*)d_out;

    dim3 block(256);
    dim3 grid(2048);   // 2048 blocks x 32-row slabs = 65536 rows exactly
    noise_learn_kernel<<<grid, block, 0, stream>>>(x, bins, eps, params, out, out_size);
}

// Round 16
// 36.478 us; speedup vs baseline: 1.3218x; 1.0177x over previous
//
#include <hip/hip_runtime.h>

// NoiseLearnModule: out = x + where(0<=bin<16, eps * sigmoid(params[f,bin]) * 0.1, 0)
// bin = searchsorted(bins[f], x, side='right') - 1
// x,eps [65536,256] f32; bins [256,17] f32; params [256*16] f32.
//
// R16 = R15 (slab blocking, zero-LDS, 1 feature/thread, fused cndmask chain,
// vectorized prologue, cached stores) with ONE change: U=8 load batching.
// All 16 loads (8 rows x {x,eps}) issue before any compute -> 4 stall points
// per thread instead of 8; ~16 loads in flight per wave.

typedef float f4u __attribute__((ext_vector_type(4), aligned(4)));  // 4B-aligned float4

#define NFEAT 256
#define NBINS 16
#define NEDGE 17
#define ROWS_PER_BLOCK 32
#define NOISE_SCALE 0.1f

__global__ __launch_bounds__(256, 4) void noise_learn_kernel(
    const float* __restrict__ x,
    const float* __restrict__ bins,
    const float* __restrict__ eps,
    const float* __restrict__ params,
    float* __restrict__ out,
    int total)
{
    const int t = threadIdx.x;               // == feature id

    // Vectorized prologue (R14): 5 loads for bins, 4 for params.
    float ed[NEDGE];
    {
        const f4u* br = reinterpret_cast<const f4u*>(bins + t * NEDGE);
        const f4u b0 = br[0], b1 = br[1], b2 = br[2], b3 = br[3];
        ed[0] = b0[0]; ed[1] = b0[1]; ed[2]  = b0[2];  ed[3]  = b0[3];
        ed[4] = b1[0]; ed[5] = b1[1]; ed[6]  = b1[2];  ed[7]  = b1[3];
        ed[8] = b2[0]; ed[9] = b2[1]; ed[10] = b2[2];  ed[11] = b2[3];
        ed[12] = b3[0]; ed[13] = b3[1]; ed[14] = b3[2]; ed[15] = b3[3];
        ed[16] = bins[t * NEDGE + 16];
    }

    float sg[NBINS];                         // pre-scaled: 0.1 * sigmoid(p)
    {
        const float4* pr = reinterpret_cast<const float4*>(params + t * NBINS); // 64B-aligned
        const float4 p0 = pr[0], p1 = pr[1], p2 = pr[2], p3 = pr[3];
        const float pp[NBINS] = { p0.x, p0.y, p0.z, p0.w,  p1.x, p1.y, p1.z, p1.w,
                                  p2.x, p2.y, p2.z, p2.w,  p3.x, p3.y, p3.z, p3.w };
        #pragma unroll
        for (int k = 0; k < NBINS; ++k)
            sg[k] = NOISE_SCALE / (1.0f + __expf(-pp[k]));
    }

// Fused scan+select with validity folded into the endpoints.
#define PROC(xv, ev, res) do {                                           \
        float s_ = (ed[0] <= (xv)) ? sg[0] : 0.0f;                       \
        s_ = (ed[1]  <= (xv)) ? sg[1]  : s_;                             \
        s_ = (ed[2]  <= (xv)) ? sg[2]  : s_;                             \
        s_ = (ed[3]  <= (xv)) ? sg[3]  : s_;                             \
        s_ = (ed[4]  <= (xv)) ? sg[4]  : s_;                             \
        s_ = (ed[5]  <= (xv)) ? sg[5]  : s_;                             \
        s_ = (ed[6]  <= (xv)) ? sg[6]  : s_;                             \
        s_ = (ed[7]  <= (xv)) ? sg[7]  : s_;                             \
        s_ = (ed[8]  <= (xv)) ? sg[8]  : s_;                             \
        s_ = (ed[9]  <= (xv)) ? sg[9]  : s_;                             \
        s_ = (ed[10] <= (xv)) ? sg[10] : s_;                             \
        s_ = (ed[11] <= (xv)) ? sg[11] : s_;                             \
        s_ = (ed[12] <= (xv)) ? sg[12] : s_;                             \
        s_ = (ed[13] <= (xv)) ? sg[13] : s_;                             \
        s_ = (ed[14] <= (xv)) ? sg[14] : s_;                             \
        s_ = (ed[15] <= (xv)) ? sg[15] : s_;                             \
        s_ = ((xv) < ed[16]) ? s_ : 0.0f;                                \
        (res) = fmaf((ev), s_, (xv));                                    \
    } while (0)

    // Slab: block b covers rows [32b, 32b+32). 4 iterations of 8 rows.
    const int base0 = blockIdx.x * (ROWS_PER_BLOCK * NFEAT) + t;

    for (int j = 0; j < ROWS_PER_BLOCK / 8; ++j) {
        const int g = base0 + j * (8 * NFEAT);
        const int gA = g,             gB = g + NFEAT,     gC = g + 2 * NFEAT, gD = g + 3 * NFEAT;
        const int gE = g + 4 * NFEAT, gF = g + 5 * NFEAT, gG = g + 6 * NFEAT, gH = g + 7 * NFEAT;

        // All 16 loads issued before any compute (16 in flight).
        const float xA = x[gA], xB = x[gB], xC = x[gC], xD = x[gD];
        const float xE = x[gE], xF = x[gF], xG = x[gG], xH = x[gH];
        const float pA = eps[gA], pB = eps[gB], pC = eps[gC], pD = eps[gD];
        const float pE = eps[gE], pF = eps[gF], pG = eps[gG], pH = eps[gH];

        float rA, rB, rC, rD, rE, rF, rG, rH;
        PROC(xA, pA, rA);
        PROC(xB, pB, rB);
        PROC(xC, pC, rC);
        PROC(xD, pD, rD);
        PROC(xE, pE, rE);
        PROC(xF, pF, rF);
        PROC(xG, pG, rG);
        PROC(xH, pH, rH);

        out[gA] = rA;
        out[gB] = rB;
        out[gC] = rC;
        out[gD] = rD;
        out[gE] = rE;
        out[gF] = rF;
        out[gG] = rG;
        out[gH] = rH;
    }
#undef PROC
}

extern "C" void kernel_launch(void* const* d_in, const int* in_sizes, int n_in,
                              void* d_out, int out_size, void* d_ws, size_t ws_size,
                              hipStream_t stream) {
    const float* x      = (const float*)d_in[0];
    const float* bins   = (const float*)d_in[1];
    const float* eps    = (const float*)d_in[2];
    const float* params = (const float*)d_in[3];
    float* out = (float*)d_out;

    dim3 block(256);
    dim3 grid(2048);   // 2048 blocks x 32-row slabs = 65536 rows exactly
    noise_learn_kernel<<<grid, block, 0, stream>>>(x, bins, eps, params, out, out_size);
}